// Round 6
// baseline (269.356 us; speedup 1.0000x reference)
//
#include <hip/hip_runtime.h>

// Problem constants
#define NB 128
#define NC 256
#define HX 31
#define WX 31
#define XCH (HX * WX)        // 961 floats per channel of x
#define HC 25          // corr spatial (31-7+1)
#define WC 25
#define HO 23          // head output spatial (25-3+1)
#define WO 23
#define CHUNKS 8       // channel chunks per batch item -> 1024 blocks (4/CU, all resident)
#define CPB (NC / CHUNKS)    // 32 channels per block
#define GRP 4                // channels per group iteration -> 8 even groups
#define ZCH 56               // z: 7 rows * 8 stride (16B-aligned rows)
#define WCH 48               // weights: 45 padded to 48, v3/v6 layout
#define CCH (HC * WC)        // 625

#define NPIX (HO * WO)               // 529
#define HEAT_SZ (NB * NPIX)          // 67712
#define REG_SZ  (NB * 4 * NPIX)      // 270848
#define OUT_TOTAL (HEAT_SZ + REG_SZ) // 338560
#define NSTRIP3 (HO * 8)             // 184 three-pixel strips (last in row = 2)
#define PART_STRIDE (5 * NPIX)       // 2645 floats per (n,chunk) partial
#define WS_NEED ((size_t)NB * CHUNKS * PART_STRIDE * sizeof(float))   // 10.8 MB

// unaligned-capable float4 (x rows / cs rows start at arbitrary dword offsets)
typedef float f4v __attribute__((ext_vector_type(4), aligned(4)));

// Fallback path only: writes bias into d_out (harness poisons d_out before launch).
__global__ void init_out_kernel(float* __restrict__ out,
                                const float* __restrict__ heat_b,
                                const float* __restrict__ reg_b) {
    int i = blockIdx.x * 256 + threadIdx.x;
    if (i >= OUT_TOTAL) return;
    if (i < HEAT_SZ) {
        out[i] = heat_b[0];
    } else {
        int j = i - HEAT_SZ;
        int o = (j / NPIX) & 3;
        out[i] = reg_b[o];
    }
}

// Reduce 8 per-chunk partials + bias -> final outputs. Overwrites poison fully.
__global__ void reduce_kernel(const float* __restrict__ part,
                              const float* __restrict__ heat_b,
                              const float* __restrict__ reg_b,
                              float* __restrict__ out) {
    int i = blockIdx.x * 256 + threadIdx.x;
    if (i >= OUT_TOTAL) return;
    int n, o, p;
    float b;
    if (i < HEAT_SZ) {
        n = i / NPIX; p = i - n * NPIX; o = 0; b = heat_b[0];
    } else {
        int j = i - HEAT_SZ;
        n = j / (4 * NPIX);
        int rm = j - n * 4 * NPIX;
        int r = rm / NPIX;
        p = rm - r * NPIX;
        o = 1 + r;
        b = reg_b[r];
    }
    const float* src = part + (size_t)n * CHUNKS * PART_STRIDE + o * NPIX + p;
    float s = b;
    #pragma unroll
    for (int c = 0; c < CHUNKS; ++c) s += src[(size_t)c * PART_STRIDE];
    out[i] = s;
}

// Fused exact-corr + head kernel, v7:
//  - x staged to LDS per group: 961 float4 loads issued in bulk by all 256
//    threads (one amortized HBM latency per group instead of 11 serialized
//    per-row waits per thread), then corr reads x from LDS
//  - GRP=4/CPB=32/CHUNKS=8: LDS 32.4KB -> 5 blocks/CU static; grid 1024 ->
//    4 blocks/CU, all resident (16 waves/CU)
//  - corr/head FMA bodies identical to v6 (proven 64-VGPR codegen)
//  - USE_WS: exclusive partial outputs (WS_NEED now 10.8MB); else atomics
template <bool USE_WS>
__launch_bounds__(256, 4)
__global__ void fused_head_kernel(const float* __restrict__ xf,
                                  const float* __restrict__ zf,
                                  const float* __restrict__ hw,
                                  const float* __restrict__ rw,
                                  float* __restrict__ out) {
    __shared__ __align__(16) float xs[GRP * XCH];       // 15.0 KB
    __shared__ __align__(16) float cs[GRP * CCH + 8];   // 10.0 KB (+pad: tail-strip overread)
    __shared__ __align__(16) float zs[GRP * ZCH];       // 0.9 KB
    __shared__ __align__(16) float ws[CPB * WCH];       // 6.0 KB

    const int tid = threadIdx.x;
    const int n = blockIdx.x >> 3;
    const int chunk = blockIdx.x & 7;
    const int cbase = chunk * CPB;

    // corr mapping: 25 threads/channel, each owns an exact 5x5 corr tile
    const int cl = tid / 25;               // channel-in-group (>=GRP -> idle)
    const int tt = tid % 25;
    const int tr = tt / 5, tc = tt % 5;
    const int i0 = tr * 5, j0 = tc * 5;

    // head mapping: 3-pixel strips. strip sid -> row sid/8, cols 3*(sid%8)..+2
    const bool hasS = (tid < NSTRIP3);     // threads 184..255 idle in head phase
    const int sy = tid >> 3;               // 0..22
    const int sx = tid & 7;                // 0..7
    const int cx = sx * 3;                 // 0,3,...,21
    const int offS = sy * WC + cx;

    float accH[3] = {0.f, 0.f, 0.f};
    float accR[4][3] = {{0.f,0.f,0.f},{0.f,0.f,0.f},{0.f,0.f,0.f},{0.f,0.f,0.f}};

    const float* xn = xf + ((size_t)n * NC + cbase) * XCH;
    const float* zn = zf + ((size_t)n * NC + cbase) * 49;

    // ---- stage all 32 channels' head weights once (v3/v6 layout) ----
    for (int idx = tid; idx < CPB * 45; idx += 256) {
        int ch = idx / 45, j = idx - ch * 45;
        int c = cbase + ch;
        float v;
        if (j < 9) {
            v = hw[c * 9 + j];
        } else {
            int o = (j - 9) / 9;
            int jj = (j - 9) - o * 9;
            v = rw[((size_t)o * NC + c) * 9 + jj];
        }
        ws[ch * WCH + j] = v;
    }

    for (int g0 = 0; g0 < CPB; g0 += GRP) {
        // ---- stage z (padded stride-8 rows) + x (bulk float4, 961 per group) ----
        if (tid < GRP * 49) {
            int ch = tid / 49, q = tid - ch * 49;
            int u = q / 7, v = q - u * 7;
            zs[ch * ZCH + u * 8 + v] = zn[(size_t)(g0 + ch) * 49 + q];
        }
        {
            const f4v* gx = (const f4v*)(xn + (size_t)g0 * XCH);  // 4B-aligned ok
            f4v* xs4 = (f4v*)xs;
            const bool t3ok = (tid < 193);                        // 961 = 3*256 + 193
            f4v t0 = gx[tid];
            f4v t1 = gx[tid + 256];
            f4v t2 = gx[tid + 512];
            f4v t3;
            if (t3ok) t3 = gx[tid + 768];
            xs4[tid]       = t0;
            xs4[tid + 256] = t1;
            xs4[tid + 512] = t2;
            if (t3ok) xs4[tid + 768] = t3;
        }
        __syncthreads();

        // ---- exact corr: x rows from LDS (latency-free), FMA body = v6 ----
        if (cl < GRP) {
            const float* xb = xs + cl * XCH + i0 * WX + j0;
            const float* zb = zs + cl * ZCH;

            float cacc[5][5];
            #pragma unroll
            for (int r = 0; r < 5; ++r)
                #pragma unroll
                for (int b = 0; b < 5; ++b) cacc[r][b] = 0.f;

            #pragma unroll
            for (int rl = 0; rl < 11; ++rl) {
                const float* rp = xb + rl * WX;
                f4v c0 = *(const f4v*)(rp);
                f4v c1 = *(const f4v*)(rp + 4);
                f4v c2 = *(const f4v*)(rp + 7);   // cols j0+7..j0+10 (max col 30)
                const float xr[11] = {c0.x, c0.y, c0.z, c0.w,
                                      c1.x, c1.y, c1.z, c1.w,
                                      c2.y, c2.z, c2.w};
                #pragma unroll
                for (int u = 0; u < 7; ++u) {
                    const int r = rl - u;           // folds at compile time
                    if (r >= 0 && r < 5) {
                        f4v za = *(const f4v*)(zb + u * 8);      // broadcast
                        f4v zc = *(const f4v*)(zb + u * 8 + 4);
                        const float zz[7] = {za.x, za.y, za.z, za.w,
                                             zc.x, zc.y, zc.z};
                        #pragma unroll
                        for (int v = 0; v < 7; ++v)
                            #pragma unroll
                            for (int b = 0; b < 5; ++b)
                                cacc[r][b] = fmaf(zz[v], xr[b + v], cacc[r][b]);
                    }
                }
            }
            float* cb = cs + cl * CCH + i0 * WC + j0;
            #pragma unroll
            for (int r = 0; r < 5; ++r)
                #pragma unroll
                for (int b = 0; b < 5; ++b) cb[r * WC + b] = cacc[r][b];
        }
        __syncthreads();

        // ---- conv heads: 3-pixel strips, w[48] broadcast tile (v6 body) ----
        if (hasS) {
            for (int clc = 0; clc < GRP; ++clc) {
                float w[48];
                {
                    const f4v* wp = (const f4v*)(ws + (size_t)(g0 + clc) * WCH);
                    #pragma unroll
                    for (int q = 0; q < 12; ++q) {     // broadcast reads
                        f4v t = wp[q];
                        w[q * 4 + 0] = t.x; w[q * 4 + 1] = t.y;
                        w[q * 4 + 2] = t.z; w[q * 4 + 3] = t.w;
                    }
                }
                const float* base = cs + clc * CCH + offS;

                #pragma unroll
                for (int dy = 0; dy < 3; ++dy) {
                    f4v f = *(const f4v*)(base + dy * WC);   // cols cx..cx+3
                    const float f4 = base[dy * WC + 4];      // col cx+4
                    #pragma unroll
                    for (int dx = 0; dx < 3; ++dx) {
                        const int k = dy * 3 + dx;
                        #pragma unroll
                        for (int px = 0; px < 3; ++px) {
                            const int e = dx + px;           // 0..4, static
                            const float cv = (e < 4) ? f[e] : f4;
                            accH[px]    = fmaf(cv, w[k],      accH[px]);
                            accR[0][px] = fmaf(cv, w[9 + k],  accR[0][px]);
                            accR[1][px] = fmaf(cv, w[18 + k], accR[1][px]);
                            accR[2][px] = fmaf(cv, w[27 + k], accR[2][px]);
                            accR[3][px] = fmaf(cv, w[36 + k], accR[3][px]);
                        }
                    }
                }
            }
        }
        __syncthreads();
    }

    // ---- epilogue ----
    if (!hasS) return;
    const int p = sy * WO + cx;
    const bool full = (sx < 7);          // last strip in row has only 2 pixels

    if (USE_WS) {
        // exclusive partial region for this (n, chunk): plain stores
        float* part = out + (size_t)(n * CHUNKS + chunk) * PART_STRIDE;
        part[p + 0] = accH[0];
        part[p + 1] = accH[1];
        if (full) part[p + 2] = accH[2];
        #pragma unroll
        for (int o = 0; o < 4; ++o) {
            float* pr = part + (1 + o) * NPIX + p;
            pr[0] = accR[o][0];
            pr[1] = accR[o][1];
            if (full) pr[2] = accR[o][2];
        }
    } else {
        // atomic fallback (bias pre-written by init kernel)
        float* outH = out + n * NPIX + p;
        float* outR = out + HEAT_SZ + (size_t)n * 4 * NPIX + p;
        atomicAdd(&outH[0], accH[0]);
        atomicAdd(&outH[1], accH[1]);
        if (full) atomicAdd(&outH[2], accH[2]);
        #pragma unroll
        for (int o = 0; o < 4; ++o) {
            float* pr = outR + o * NPIX;
            atomicAdd(&pr[0], accR[o][0]);
            atomicAdd(&pr[1], accR[o][1]);
            if (full) atomicAdd(&pr[2], accR[o][2]);
        }
    }
}

extern "C" void kernel_launch(void* const* d_in, const int* in_sizes, int n_in,
                              void* d_out, int out_size, void* d_ws, size_t ws_size,
                              hipStream_t stream) {
    const float* x_f    = (const float*)d_in[0];
    const float* z_f    = (const float*)d_in[1];
    const float* heat_w = (const float*)d_in[2];
    const float* heat_b = (const float*)d_in[3];
    const float* reg_w  = (const float*)d_in[4];
    const float* reg_b  = (const float*)d_in[5];
    float* out = (float*)d_out;

    if (d_ws != nullptr && ws_size >= WS_NEED) {
        fused_head_kernel<true><<<NB * CHUNKS, 256, 0, stream>>>(
            x_f, z_f, heat_w, reg_w, (float*)d_ws);
        reduce_kernel<<<(OUT_TOTAL + 255) / 256, 256, 0, stream>>>(
            (const float*)d_ws, heat_b, reg_b, out);
    } else {
        init_out_kernel<<<(OUT_TOTAL + 255) / 256, 256, 0, stream>>>(out, heat_b, reg_b);
        fused_head_kernel<false><<<NB * CHUNKS, 256, 0, stream>>>(
            x_f, z_f, heat_w, reg_w, out);
    }
}

// Round 8
// 258.898 us; speedup vs baseline: 1.0404x; 1.0404x over previous
//
#include <hip/hip_runtime.h>

// Problem constants
#define NB 128
#define NC 256
#define HX 31
#define WX 31
#define HC 25          // corr spatial (31-7+1)
#define WC 25
#define HO 23          // head output spatial (25-3+1)
#define WO 23
#define CHUNKS 16      // channel chunks per batch item -> 2048 blocks
#define CPB (NC / CHUNKS)    // 16 channels per block
#define GRP 8                // channels per group iteration -> 2 even groups
#define ZCH 56               // z: 7 rows * 8 stride (16B-aligned rows)
#define WCH 48               // weights: 45 padded to 48, v3/v6 layout
#define CCH (HC * WC)        // 625

#define NPIX (HO * WO)               // 529
#define HEAT_SZ (NB * NPIX)          // 67712
#define REG_SZ  (NB * 4 * NPIX)      // 270848
#define OUT_TOTAL (HEAT_SZ + REG_SZ) // 338560
#define NSTRIP3 (HO * 8)             // 184 three-pixel strips (last in row = 2)
#define PART_STRIDE (5 * NPIX)       // 2645 floats per (n,chunk) partial
#define WS_NEED ((size_t)NB * CHUNKS * PART_STRIDE * sizeof(float))

// unaligned-capable float4 (x rows / cs rows start at arbitrary dword offsets)
typedef float f4v __attribute__((ext_vector_type(4), aligned(4)));

// Fallback path only: writes bias into d_out (harness poisons d_out before launch).
__global__ void init_out_kernel(float* __restrict__ out,
                                const float* __restrict__ heat_b,
                                const float* __restrict__ reg_b) {
    int i = blockIdx.x * 256 + threadIdx.x;
    if (i >= OUT_TOTAL) return;
    if (i < HEAT_SZ) {
        out[i] = heat_b[0];
    } else {
        int j = i - HEAT_SZ;
        int o = (j / NPIX) & 3;
        out[i] = reg_b[o];
    }
}

// Reduce 16 per-chunk partials + bias -> final outputs. Overwrites poison fully.
__global__ void reduce_kernel(const float* __restrict__ part,
                              const float* __restrict__ heat_b,
                              const float* __restrict__ reg_b,
                              float* __restrict__ out) {
    int i = blockIdx.x * 256 + threadIdx.x;
    if (i >= OUT_TOTAL) return;
    int n, o, p;
    float b;
    if (i < HEAT_SZ) {
        n = i / NPIX; p = i - n * NPIX; o = 0; b = heat_b[0];
    } else {
        int j = i - HEAT_SZ;
        n = j / (4 * NPIX);
        int rm = j - n * 4 * NPIX;
        int r = rm / NPIX;
        p = rm - r * NPIX;
        o = 1 + r;
        b = reg_b[r];
    }
    const float* src = part + (size_t)n * CHUNKS * PART_STRIDE + o * NPIX + p;
    float s = b;
    #pragma unroll
    for (int c = 0; c < CHUNKS; ++c) s += src[(size_t)c * PART_STRIDE];
    out[i] = s;
}

// Fused exact-corr + head kernel, v8 = v6 +:
//  - XCD-affinity block remap: all 16 chunks of batch item n land on XCD n%8
//    (blockIdx round-robins XCDs by %8) -> the out[n] atomic RMW lines stay
//    in ONE L2 instead of bouncing across 8 non-coherent L2s
//    (v6: 15.5 B/atomic HBM write; v7 at 1 block/XCD: 49 B/atomic = full
//    line writeback per atomic)
//  - corr: 3-deep register prefetch ring (buf[3][3]); loads for row rl+3
//    issued before row rl's FMA body -> ~3 FMA-bodies (~660 cyc) of slack
//    vs v6's 1-row (~220 cyc) against ~900 cyc HBM latency (x never L2-fits)
//  - head phase / LDS layout / epilogue identical to v6 (proven codegen)
template <bool USE_WS>
__launch_bounds__(256, 4)
__global__ void fused_head_kernel(const float* __restrict__ xf,
                                  const float* __restrict__ zf,
                                  const float* __restrict__ hw,
                                  const float* __restrict__ rw,
                                  float* __restrict__ out) {
    __shared__ __align__(16) float cs[GRP * CCH + 8];   // 20.0 KB (+pad: tail-strip overread)
    __shared__ __align__(16) float zs[GRP * ZCH];       // 1.8 KB
    __shared__ __align__(16) float ws[CPB * WCH];       // 3.0 KB

    const int tid = threadIdx.x;
    // XCD-affinity decode (bijective for grid 2048):
    //   xcd = b&7, k = b>>3; n = xcd + 8*(k>>4); chunk = k&15
    // -> all blocks of a given n share b%8 (same XCD under round-robin).
    const int b = blockIdx.x;
    const int n = (b & 7) + 8 * ((b >> 3) >> 4);
    const int chunk = (b >> 3) & 15;
    const int cbase = chunk * CPB;

    // corr mapping: 25 threads/channel, each owns an exact 5x5 corr tile
    const int cl = tid / 25;               // channel-in-group (>=GRP -> idle)
    const int tt = tid % 25;
    const int tr = tt / 5, tc = tt % 5;
    const int i0 = tr * 5, j0 = tc * 5;

    // head mapping: 3-pixel strips. strip sid -> row sid/8, cols 3*(sid%8)..+2
    const bool hasS = (tid < NSTRIP3);     // threads 184..255 idle in head phase
    const int sy = tid >> 3;               // 0..22
    const int sx = tid & 7;                // 0..7
    const int cx = sx * 3;                 // 0,3,...,21
    const int offS = sy * WC + cx;

    float accH[3] = {0.f, 0.f, 0.f};
    float accR[4][3] = {{0.f,0.f,0.f},{0.f,0.f,0.f},{0.f,0.f,0.f},{0.f,0.f,0.f}};

    const float* xn = xf + ((size_t)n * NC + cbase) * (HX * WX);
    const float* zn = zf + ((size_t)n * NC + cbase) * 49;

    // ---- stage all 16 channels' head weights once (v3/v6 layout) ----
    for (int idx = tid; idx < CPB * 45; idx += 256) {
        int ch = idx / 45, j = idx - ch * 45;
        int c = cbase + ch;
        float v;
        if (j < 9) {
            v = hw[c * 9 + j];
        } else {
            int o = (j - 9) / 9;
            int jj = (j - 9) - o * 9;
            v = rw[((size_t)o * NC + c) * 9 + jj];
        }
        ws[ch * WCH + j] = v;
    }

    for (int g0 = 0; g0 < CPB; g0 += GRP) {
        // ---- stage z, rows padded to stride 8 for aligned reads ----
        for (int idx = tid; idx < GRP * 49; idx += 256) {
            int ch = idx / 49, q = idx - ch * 49;
            int u = q / 7, v = q - u * 7;
            zs[ch * ZCH + u * 8 + v] = zn[(size_t)(g0 + ch) * 49 + q];
        }
        __syncthreads();

        // ---- exact corr: x from global via 3-deep row prefetch ring ----
        if (cl < GRP) {
            const float* xb = xn + (size_t)(g0 + cl) * (HX * WX) + i0 * WX + j0;
            const float* zb = zs + cl * ZCH;

            float cacc[5][5];
            #pragma unroll
            for (int r = 0; r < 5; ++r)
                #pragma unroll
                for (int b2 = 0; b2 < 5; ++b2) cacc[r][b2] = 0.f;

            f4v buf[3][3];
            #pragma unroll
            for (int r = 0; r < 3; ++r) {
                const float* rp = xb + r * WX;
                buf[r][0] = *(const f4v*)(rp);
                buf[r][1] = *(const f4v*)(rp + 4);
                buf[r][2] = *(const f4v*)(rp + 7);   // cols j0+7..j0+10 (max col 30)
            }

            #pragma unroll
            for (int rl = 0; rl < 11; ++rl) {
                const int slot = rl % 3;             // static under full unroll
                const float xr[11] = {buf[slot][0].x, buf[slot][0].y,
                                      buf[slot][0].z, buf[slot][0].w,
                                      buf[slot][1].x, buf[slot][1].y,
                                      buf[slot][1].z, buf[slot][1].w,
                                      buf[slot][2].y, buf[slot][2].z,
                                      buf[slot][2].w};
                if (rl + 3 < 11) {                   // refill freed slot early
                    const float* rp = xb + (rl + 3) * WX;
                    buf[slot][0] = *(const f4v*)(rp);
                    buf[slot][1] = *(const f4v*)(rp + 4);
                    buf[slot][2] = *(const f4v*)(rp + 7);
                }
                #pragma unroll
                for (int u = 0; u < 7; ++u) {
                    const int r = rl - u;            // folds at compile time
                    if (r >= 0 && r < 5) {
                        f4v za = *(const f4v*)(zb + u * 8);      // broadcast
                        f4v zc = *(const f4v*)(zb + u * 8 + 4);
                        const float zz[7] = {za.x, za.y, za.z, za.w,
                                             zc.x, zc.y, zc.z};
                        #pragma unroll
                        for (int v = 0; v < 7; ++v)
                            #pragma unroll
                            for (int b2 = 0; b2 < 5; ++b2)
                                cacc[r][b2] = fmaf(zz[v], xr[b2 + v], cacc[r][b2]);
                    }
                }
            }
            float* cb = cs + cl * CCH + i0 * WC + j0;
            #pragma unroll
            for (int r = 0; r < 5; ++r)
                #pragma unroll
                for (int b2 = 0; b2 < 5; ++b2) cb[r * WC + b2] = cacc[r][b2];
        }
        __syncthreads();

        // ---- conv heads: 3-pixel strips, w[48] broadcast tile (v6 body) ----
        if (hasS) {
            for (int clc = 0; clc < GRP; ++clc) {
                float w[48];
                {
                    const f4v* wp = (const f4v*)(ws + (size_t)(g0 + clc) * WCH);
                    #pragma unroll
                    for (int q = 0; q < 12; ++q) {     // broadcast reads
                        f4v t = wp[q];
                        w[q * 4 + 0] = t.x; w[q * 4 + 1] = t.y;
                        w[q * 4 + 2] = t.z; w[q * 4 + 3] = t.w;
                    }
                }
                const float* base = cs + clc * CCH + offS;

                #pragma unroll
                for (int dy = 0; dy < 3; ++dy) {
                    f4v f = *(const f4v*)(base + dy * WC);   // cols cx..cx+3
                    const float f4 = base[dy * WC + 4];      // col cx+4
                    #pragma unroll
                    for (int dx = 0; dx < 3; ++dx) {
                        const int k = dy * 3 + dx;
                        #pragma unroll
                        for (int px = 0; px < 3; ++px) {
                            const int e = dx + px;           // 0..4, static
                            const float cv = (e < 4) ? f[e] : f4;
                            accH[px]    = fmaf(cv, w[k],      accH[px]);
                            accR[0][px] = fmaf(cv, w[9 + k],  accR[0][px]);
                            accR[1][px] = fmaf(cv, w[18 + k], accR[1][px]);
                            accR[2][px] = fmaf(cv, w[27 + k], accR[2][px]);
                            accR[3][px] = fmaf(cv, w[36 + k], accR[3][px]);
                        }
                    }
                }
            }
        }
        __syncthreads();
    }

    // ---- epilogue ----
    if (!hasS) return;
    const int p = sy * WO + cx;
    const bool full = (sx < 7);          // last strip in row has only 2 pixels

    if (USE_WS) {
        // exclusive partial region for this (n, chunk): plain stores
        float* part = out + (size_t)(n * CHUNKS + chunk) * PART_STRIDE;
        part[p + 0] = accH[0];
        part[p + 1] = accH[1];
        if (full) part[p + 2] = accH[2];
        #pragma unroll
        for (int o = 0; o < 4; ++o) {
            float* pr = part + (1 + o) * NPIX + p;
            pr[0] = accR[o][0];
            pr[1] = accR[o][1];
            if (full) pr[2] = accR[o][2];
        }
    } else {
        // atomic fallback (bias pre-written by init kernel); with the XCD
        // remap all atomics for out[n] stay on one XCD's L2.
        float* outH = out + n * NPIX + p;
        float* outR = out + HEAT_SZ + (size_t)n * 4 * NPIX + p;
        atomicAdd(&outH[0], accH[0]);
        atomicAdd(&outH[1], accH[1]);
        if (full) atomicAdd(&outH[2], accH[2]);
        #pragma unroll
        for (int o = 0; o < 4; ++o) {
            float* pr = outR + o * NPIX;
            atomicAdd(&pr[0], accR[o][0]);
            atomicAdd(&pr[1], accR[o][1]);
            if (full) atomicAdd(&pr[2], accR[o][2]);
        }
    }
}

extern "C" void kernel_launch(void* const* d_in, const int* in_sizes, int n_in,
                              void* d_out, int out_size, void* d_ws, size_t ws_size,
                              hipStream_t stream) {
    const float* x_f    = (const float*)d_in[0];
    const float* z_f    = (const float*)d_in[1];
    const float* heat_w = (const float*)d_in[2];
    const float* heat_b = (const float*)d_in[3];
    const float* reg_w  = (const float*)d_in[4];
    const float* reg_b  = (const float*)d_in[5];
    float* out = (float*)d_out;

    if (d_ws != nullptr && ws_size >= WS_NEED) {
        fused_head_kernel<true><<<NB * CHUNKS, 256, 0, stream>>>(
            x_f, z_f, heat_w, reg_w, (float*)d_ws);
        reduce_kernel<<<(OUT_TOTAL + 255) / 256, 256, 0, stream>>>(
            (const float*)d_ws, heat_b, reg_b, out);
    } else {
        init_out_kernel<<<(OUT_TOTAL + 255) / 256, 256, 0, stream>>>(out, heat_b, reg_b);
        fused_head_kernel<false><<<NB * CHUNKS, 256, 0, stream>>>(
            x_f, z_f, heat_w, reg_w, out);
    }
}